// Round 9
// baseline (484.607 us; speedup 1.0000x reference)
//
#include <hip/hip_runtime.h>

typedef __attribute__((ext_vector_type(8))) _Float16 halfx8;
typedef __attribute__((ext_vector_type(4))) float f32x4;

#define MFMA16H(a, b, c) __builtin_amdgcn_mfma_f32_16x16x32_f16(a, b, c, 0, 0, 0)

#define T_SEQ 512
#define F_IN 32
#define H1 128
#define E2 64
#define ROWS 4          // batch rows per block

__device__ __forceinline__ ushort f2h(float f) {
    _Float16 h = (_Float16)f;              // v_cvt_f16_f32, RNE
    return __builtin_bit_cast(ushort, h);
}
__device__ __forceinline__ float fast_sigmoid(float x) {
    float e = __expf(-x);
    return __builtin_amdgcn_rcpf(1.0f + e);
}
__device__ __forceinline__ float fast_tanh(float x) {
    float e = __expf(-2.0f * x);
    return 2.0f * __builtin_amdgcn_rcpf(1.0f + e) - 1.0f;
}
__device__ __forceinline__ halfx8 load_w8h(const float* p) {
    halfx8 r;
#pragma unroll
    for (int j = 0; j < 8; ++j) r[j] = (_Float16)p[j];
    return r;
}

// Fused 2-layer LSTM, 128 blocks x 512 threads (8 waves), 4 batch rows/blk.
//
// ROUND THEORY (overlap epilogue with MFMA pipe drain): r8 = 2025 cyc/step;
// active-CU MfmaUtil 52% (= 64 MFMA/SIMD x 20.6 cyc pipe = 1320) + VALU 39%
// barely overlap (sum 91%) because the kt-outer/tau-inner K-loop makes ALL
// accumulators finish at pipe-end -> whole epilogue serial after. Fix:
//  - L1 split into two gate-groups (uo=0, uo=1). Issue group-A's 20 MFMAs,
//    then group-B's 20, THEN epilogue-A (its accs completed mid-pipe; its
//    VALU runs while B's MFMAs drain), then epilogue-B (only exposed part).
//  - x A-fragment carried across iterations (xs[t] written 8 steps early):
//    first MFMA issues at barrier-exit instead of after ~120cyc ds_read.
//  - L2 unchanged (4 accs feed one epilogue; its short 24-MFMA stream
//    already self-hides under L1's).
// Per-acc accumulate order (x, kt0..3) unchanged -> bit-identical numerics.
__global__ __launch_bounds__(512, 1) void lstm_fused(
    const float* __restrict__ x,      // [512][512][32]
    const float* __restrict__ Wih1,   // [512][32]
    const float* __restrict__ Whh1,   // [512][128]
    const float* __restrict__ bih1,   // [512]
    const float* __restrict__ bhh1,   // [512]
    const float* __restrict__ Wih2,   // [256][128]
    const float* __restrict__ Whh2,   // [256][64]
    const float* __restrict__ bih2,   // [256]
    const float* __restrict__ bhh2,   // [256]
    float* __restrict__ out)          // [512][64] fp32
{
    __shared__ __align__(16) ushort xs [16][ROWS][80];  // fp16 x(t) ring, cols 0..31
    __shared__ __align__(16) ushort h1s[2][ROWS][144];  // fp16 h1, cols 0..127
    __shared__ __align__(16) ushort h2s[2][ROWS][80];   // fp16 h2, cols 0..63

    const int tid  = threadIdx.x;
    const int wave = tid >> 6;
    const int lane = tid & 63;
    const int l15  = lane & 15;
    const int quad = lane >> 4;
    const int arow = l15 >> 2;        // broadcast A-row (batch row) for ds_reads
    const int r0   = blockIdx.x * ROWS;
    const bool isL1 = (wave < 4);
    const int w    = wave & 3;

    // Weight fragment file (disjoint per wave group), fp16:
    //  L1 (tau = g*2+uo): wf[tau*4+kt] = Whh1 frag, wf[32+tau] = Wih1 frag
    //  L2 (g):            wf[g*4+kt]   = Wih2 frag, wf[16+g*2+kc] = Whh2 frag
    halfx8 wf[40];
    float  bias[8];

    if (isL1) {
#pragma unroll
        for (int g = 0; g < 4; ++g)
#pragma unroll
            for (int uo = 0; uo < 2; ++uo) {
                const int tau = g * 2 + uo;
                const int n = g * 128 + w * 32 + uo * 16 + l15;
#pragma unroll
                for (int kt = 0; kt < 4; ++kt)
                    wf[tau * 4 + kt] = load_w8h(Whh1 + n * H1 + kt * 32 + quad * 8);
                wf[32 + tau] = load_w8h(Wih1 + n * F_IN + quad * 8);
                bias[tau] = bih1[n] + bhh1[n];
            }
    } else {
#pragma unroll
        for (int g = 0; g < 4; ++g) {
            const int n = g * 64 + w * 16 + l15;
#pragma unroll
            for (int kt = 0; kt < 4; ++kt)
                wf[g * 4 + kt] = load_w8h(Wih2 + n * H1 + kt * 32 + quad * 8);
#pragma unroll
            for (int kc = 0; kc < 2; ++kc)
                wf[16 + g * 2 + kc] = load_w8h(Whh2 + n * E2 + kc * 32 + quad * 8);
            bias[g] = bih2[n] + bhh2[n];
        }
    }

    // zero both h-state buffers (fp16 zero == 0 bits)
    for (int i = tid; i < 2 * ROWS * 144; i += 512) ((ushort*)h1s)[i] = 0;
    for (int i = tid; i < 2 * ROWS * 80;  i += 512) ((ushort*)h2s)[i] = 0;

    // cell states: lane (quad,l15) owns batch row 'quad'
    float cst[2] = {0.0f, 0.0f};      // L1: per uo; L2 uses cst[0]

    // x staging: 32 lanes of each L2 wave; wave 4+xr stages batch row xr.
    const int xrow = w;               // for L2 waves
    const int xcol = lane;            // 0..31 valid
    const bool stager = (!isL1) && (lane < 32);
    const float* xptr = x + ((size_t)(r0 + xrow) * T_SEQ) * F_IN + xcol;
    float xr8[8];
#pragma unroll
    for (int j = 0; j < 8; ++j) xr8[j] = 0.0f;
    if (stager) {
        // prologue: stage t=0..7 into slots 0..7, prefetch t=8..15 into regs
        float t0[8];
#pragma unroll
        for (int j = 0; j < 8; ++j) t0[j] = xptr[(size_t)j * F_IN];
#pragma unroll
        for (int j = 0; j < 8; ++j) xs[j][xrow][xcol] = f2h(t0[j]);
#pragma unroll
        for (int j = 0; j < 8; ++j) xr8[j] = xptr[(size_t)(8 + j) * F_IN];
    }
    __syncthreads();

    // carried x A-fragment (xs[t] is written >= 8 steps before use)
    halfx8 ax;
    if (isL1) ax = *(const halfx8*)&xs[0][arow][quad * 8];

#pragma unroll 1
    for (int tt = 0; tt <= T_SEQ; ++tt) {
        const int p  = tt & 1;
        const int pn = p ^ 1;

        if (isL1) {
            if (tt < T_SEQ) {
                // ---- L1 GEMM: two gate-groups of 4 chains, K = 32 + 128 ----
                f32x4 aA[4], aB[4];
#pragma unroll
                for (int g = 0; g < 4; ++g) {
                    const float bA = bias[g * 2], bB = bias[g * 2 + 1];
                    aA[g] = (f32x4){bA, bA, bA, bA};
                    aB[g] = (f32x4){bB, bB, bB, bB};
                }
                halfx8 hf[4];
#pragma unroll
                for (int kt = 0; kt < 4; ++kt)
                    hf[kt] = *(const halfx8*)&h1s[p][arow][kt * 32 + quad * 8];
                __builtin_amdgcn_s_setprio(1);
                // group A (uo=0): taus 0,2,4,6
#pragma unroll
                for (int g = 0; g < 4; ++g)
                    aA[g] = MFMA16H(ax, wf[32 + g * 2], aA[g]);
#pragma unroll
                for (int kt = 0; kt < 4; ++kt)
#pragma unroll
                    for (int g = 0; g < 4; ++g)
                        aA[g] = MFMA16H(hf[kt], wf[(g * 2) * 4 + kt], aA[g]);
                // group B (uo=1): taus 1,3,5,7
#pragma unroll
                for (int g = 0; g < 4; ++g)
                    aB[g] = MFMA16H(ax, wf[32 + g * 2 + 1], aB[g]);
#pragma unroll
                for (int kt = 0; kt < 4; ++kt)
#pragma unroll
                    for (int g = 0; g < 4; ++g)
                        aB[g] = MFMA16H(hf[kt], wf[(g * 2 + 1) * 4 + kt], aB[g]);
                __builtin_amdgcn_s_setprio(0);
                // ---- epilogue A (uo=0): runs while group-B MFMAs drain ----
                {
                    const int u = w * 32 + l15;
                    const float iv = fast_sigmoid(aA[0][0]);
                    const float fv = fast_sigmoid(aA[1][0]);
                    const float gv = fast_tanh   (aA[2][0]);
                    const float ov = fast_sigmoid(aA[3][0]);
                    const float cn = fv * cst[0] + iv * gv;
                    cst[0] = cn;
                    const float h = ov * fast_tanh(cn);
                    h1s[pn][quad][u] = f2h(h);
                }
                // ---- epilogue B (uo=1): the only exposed tail ----
                {
                    const int u = w * 32 + 16 + l15;
                    const float iv = fast_sigmoid(aB[0][0]);
                    const float fv = fast_sigmoid(aB[1][0]);
                    const float gv = fast_tanh   (aB[2][0]);
                    const float ov = fast_sigmoid(aB[3][0]);
                    const float cn = fv * cst[1] + iv * gv;
                    cst[1] = cn;
                    const float h = ov * fast_tanh(cn);
                    h1s[pn][quad][u] = f2h(h);
                }
                // preload next step's x fragment (slot written >=8 steps ago)
                if (tt + 1 < T_SEQ)
                    ax = *(const halfx8*)&xs[(tt + 1) & 15][arow][quad * 8];
            }
        } else {
            if (tt >= 1) {
                // ---- L2 GEMM: 4 gates x 16 units, K = 128(h1) + 64(h2) ----
                f32x4 acc2[4];
#pragma unroll
                for (int g = 0; g < 4; ++g)
                    acc2[g] = (f32x4){bias[g], bias[g], bias[g], bias[g]};
                __builtin_amdgcn_s_setprio(1);
#pragma unroll
                for (int kt = 0; kt < 4; ++kt) {
                    const halfx8 a = *(const halfx8*)&h1s[p][arow][kt * 32 + quad * 8];
#pragma unroll
                    for (int g = 0; g < 4; ++g)
                        acc2[g] = MFMA16H(a, wf[g * 4 + kt], acc2[g]);
                }
#pragma unroll
                for (int kc = 0; kc < 2; ++kc) {
                    const halfx8 a = *(const halfx8*)&h2s[p][arow][kc * 32 + quad * 8];
#pragma unroll
                    for (int g = 0; g < 4; ++g)
                        acc2[g] = MFMA16H(a, wf[16 + g * 2 + kc], acc2[g]);
                }
                __builtin_amdgcn_s_setprio(0);
                // ---- L2 epilogue, in-register, all 64 lanes ----
                const int u = w * 16 + l15;
                const float iv = fast_sigmoid(acc2[0][0]);
                const float fv = fast_sigmoid(acc2[1][0]);
                const float gv = fast_tanh   (acc2[2][0]);
                const float ov = fast_sigmoid(acc2[3][0]);
                const float cn = fv * cst[0] + iv * gv;
                cst[0] = cn;
                const float h = ov * fast_tanh(cn);
                if (tt == T_SEQ) {
                    out[(size_t)(r0 + quad) * E2 + u] = h;
                } else {
                    h2s[pn][quad][u] = f2h(h);
                }
            }
            // ---- batched x staging, once every 8 steps ----
            if (stager && (tt & 7) == 0) {
#pragma unroll
                for (int j = 0; j < 8; ++j) {
                    const int t = tt + 8 + j;
                    if (t < T_SEQ) xs[t & 15][xrow][xcol] = f2h(xr8[j]);
                }
#pragma unroll
                for (int j = 0; j < 8; ++j) {
                    const int t = tt + 16 + j;
                    if (t < T_SEQ) xr8[j] = xptr[(size_t)t * F_IN];
                }
            }
        }
        __syncthreads();   // single barrier: buf pn complete, buf p reads done
    }
}

extern "C" void kernel_launch(void* const* d_in, const int* in_sizes, int n_in,
                              void* d_out, int out_size, void* d_ws, size_t ws_size,
                              hipStream_t stream) {
    lstm_fused<<<128, 512, 0, stream>>>(
        (const float*)d_in[0], (const float*)d_in[1], (const float*)d_in[2],
        (const float*)d_in[3], (const float*)d_in[4], (const float*)d_in[5],
        (const float*)d_in[6], (const float*)d_in[7], (const float*)d_in[8],
        (float*)d_out);
}